// Round 5
// baseline (142.153 us; speedup 1.0000x reference)
//
#include <hip/hip_runtime.h>
#include <stdint.h>
#include <math.h>

static constexpr int NN  = 1024;   // N
static constexpr int DIN = 512;    // D_IN
static constexpr int DD  = 128;    // D_OUT

// ---- threefry2x32, key = jax.random.key(42) => (0,42), partitionable ----
__device__ __forceinline__ uint32_t rotl32(uint32_t x, uint32_t r) {
  return (x << r) | (x >> (32u - r));
}

__device__ __forceinline__ bool keep_mask(uint32_t idx) {
  uint32_t x0 = 0u, x1 = idx;
  const uint32_t k0 = 0u, k1 = 42u;
  const uint32_t k2 = k0 ^ k1 ^ 0x1BD11BDAu;
  x0 += k0; x1 += k1;
#define TF_ROUND(r) { x0 += x1; x1 = rotl32(x1, r); x1 ^= x0; }
  TF_ROUND(13u) TF_ROUND(15u) TF_ROUND(26u) TF_ROUND(6u)
  x0 += k1; x1 += k2 + 1u;
  TF_ROUND(17u) TF_ROUND(29u) TF_ROUND(16u) TF_ROUND(24u)
  x0 += k2; x1 += k0 + 2u;
  TF_ROUND(13u) TF_ROUND(15u) TF_ROUND(26u) TF_ROUND(6u)
  x0 += k0; x1 += k1 + 3u;
  TF_ROUND(17u) TF_ROUND(29u) TF_ROUND(16u) TF_ROUND(24u)
  x0 += k1; x1 += k2 + 4u;
  TF_ROUND(13u) TF_ROUND(15u) TF_ROUND(26u) TF_ROUND(6u)
  x0 += k2; x1 += k0 + 5u;
#undef TF_ROUND
  const uint32_t bits = x0 ^ x1;
  const float u = __uint_as_float((bits >> 9) | 0x3f800000u) - 1.0f;
  return u < 0.6f;
}

// ---- K1: q,k,v,scale = x_i @ W.T + b  (grid (64,4), block 256) -----------
// 16 n-rows x 128 d per block, 2 n-rows per thread: each W float2 LDS read
// feeds 8 FMAs (~2 B/FMA) vs 4 in the 8-row variant. 256 blocks = 1/CU.
__global__ __launch_bounds__(256) void lin_kernel(
    const float* __restrict__ x1, const float* __restrict__ x2,
    const float* __restrict__ x3, const float* __restrict__ x4,
    const float* __restrict__ W, const float* __restrict__ bias,
    float* __restrict__ q, float* __restrict__ kk,
    float* __restrict__ v, float* __restrict__ sc) {
  __shared__ float Ws[128 * 66];
  __shared__ float Xs[16 * 68];
  const int t = threadIdx.x;
  const int n0 = blockIdx.x * 16;
  const int mat = blockIdx.y;
  const float* x = (mat == 0) ? x1 : (mat == 1) ? x2 : (mat == 2) ? x3 : x4;
  float* o = (mat == 0) ? q : (mat == 1) ? kk : (mat == 2) ? v : sc;
  const int tx = t & 31;   // d-lane: owns d = tx + 32j
  const int ty = t >> 5;   // n-pair: n = n0 + ty*2 + r
  float acc[2][4] = {{0.f, 0.f, 0.f, 0.f}, {0.f, 0.f, 0.f, 0.f}};
  for (int kt = 0; kt < 8; ++kt) {
    const int k0 = kt * 64;
    __syncthreads();
    // stage W tile 128x64 (stride 66: b64 reads land 2-way -> free, m136)
    for (int it = 0; it < 8; ++it) {
      const int i = t + 256 * it;
      const int r = i >> 4, c = (i & 15) * 4;
      const float4 wv = *(const float4*)&W[r * DIN + k0 + c];
      *(float2*)&Ws[r * 66 + c]     = make_float2(wv.x, wv.y);
      *(float2*)&Ws[r * 66 + c + 2] = make_float2(wv.z, wv.w);
    }
    // stage X tile 16x64
    {
      const int r = t >> 4, c = (t & 15) * 4;
      *(float4*)&Xs[r * 68 + c] = *(const float4*)&x[(n0 + r) * DIN + k0 + c];
    }
    __syncthreads();
    for (int c4 = 0; c4 < 64; c4 += 4) {
      const float4 xa = *(const float4*)&Xs[(ty * 2 + 0) * 68 + c4];
      const float4 xb = *(const float4*)&Xs[(ty * 2 + 1) * 68 + c4];
#pragma unroll
      for (int j = 0; j < 4; ++j) {
        const float2 w0 = *(const float2*)&Ws[(tx + 32 * j) * 66 + c4];
        const float2 w1 = *(const float2*)&Ws[(tx + 32 * j) * 66 + c4 + 2];
        acc[0][j] = fmaf(xa.x, w0.x, fmaf(xa.y, w0.y, fmaf(xa.z, w1.x, fmaf(xa.w, w1.y, acc[0][j]))));
        acc[1][j] = fmaf(xb.x, w0.x, fmaf(xb.y, w0.y, fmaf(xb.z, w1.x, fmaf(xb.w, w1.y, acc[1][j]))));
      }
    }
  }
#pragma unroll
  for (int r = 0; r < 2; ++r)
#pragma unroll
    for (int j = 0; j < 4; ++j) {
      const int d = tx + 32 * j;
      o[(n0 + ty * 2 + r) * DD + d] = acc[r][j] + bias[d];
    }
}

// ---- K2: fused qk = q@k.T (blocks 0..255) + colsoftmax (blocks 256..383) -
__global__ __launch_bounds__(256) void mid_kernel(
    const float* __restrict__ q, const float* __restrict__ kref,
    const float* __restrict__ sc, float* __restrict__ qkout,
    float* __restrict__ inv) {
  const int t = threadIdx.x;
  if (blockIdx.x < 256) {
    // ---- qk: 64x64 tile, 4x4 per thread ----
    __shared__ float qs[64 * 132];
    __shared__ float ks[64 * 132];
    const int tx = t & 15, ty = t >> 4;
    const int tm = (blockIdx.x & 15) * 64, tn = (blockIdx.x >> 4) * 64;
    for (int it = 0; it < 8; ++it) {
      const int i = t + 256 * it;
      const int r = i >> 5, c = (i & 31) * 4;
      *(float4*)&qs[r * 132 + c] = *(const float4*)&q[(tn + r) * DD + c];
      *(float4*)&ks[r * 132 + c] = *(const float4*)&kref[(tm + r) * DD + c];
    }
    __syncthreads();
    float acc[4][4] = {};
    for (int k0 = 0; k0 < DD; k0 += 4) {
      float4 qv[4], kv[4];
#pragma unroll
      for (int i = 0; i < 4; ++i) qv[i] = *(const float4*)&qs[(ty * 4 + i) * 132 + k0];
#pragma unroll
      for (int j = 0; j < 4; ++j) kv[j] = *(const float4*)&ks[(tx + 16 * j) * 132 + k0];
#pragma unroll
      for (int i = 0; i < 4; ++i)
#pragma unroll
        for (int j = 0; j < 4; ++j)
          acc[i][j] = fmaf(qv[i].x, kv[j].x,
                      fmaf(qv[i].y, kv[j].y,
                      fmaf(qv[i].z, kv[j].z,
                      fmaf(qv[i].w, kv[j].w, acc[i][j]))));
    }
#pragma unroll
    for (int i = 0; i < 4; ++i)
#pragma unroll
      for (int j = 0; j < 4; ++j)
        qkout[(size_t)(tn + ty * 4 + i) * NN + tm + tx + 16 * j] = acc[i][j];
  } else {
    // ---- column softmax over n for d = blockIdx.x - 256 ----
    __shared__ float red[256];
    const int d = blockIdx.x - 256;
    float vals[4];
    float mx = -INFINITY;
#pragma unroll
    for (int i = 0; i < 4; ++i) {
      vals[i] = sc[(size_t)(t + 256 * i) * DD + d];
      mx = fmaxf(mx, vals[i]);
    }
    red[t] = mx; __syncthreads();
    for (int s = 128; s > 0; s >>= 1) {
      if (t < s) red[t] = fmaxf(red[t], red[t + s]);
      __syncthreads();
    }
    mx = red[0]; __syncthreads();
    float e[4]; float sm = 0.f;
#pragma unroll
    for (int i = 0; i < 4; ++i) { e[i] = expf(vals[i] - mx); sm += e[i]; }
    red[t] = sm; __syncthreads();
    for (int s = 128; s > 0; s >>= 1) {
      if (t < s) red[t] += red[t + s];
      __syncthreads();
    }
    sm = red[0];
#pragma unroll
    for (int i = 0; i < 4; ++i)
      inv[(size_t)(t + 256 * i) * DD + d] = e[i] / sm;
  }
}

// ---- K3: sparse softmax-dropout-PV  (grid 1024, block 256) ---------------
// Survivor gate: qv > qkmax - 30*max_d(inv) => ~1-3 survivors of 1024.
// Thread t owns k4=(t&31)*4 and d in {g*8 + (t>>5)} -> store g covers
// out[n*16384 + g*1024 + t*4]: 1 KB contiguous per wave-store (no partial
// cachelines; fixed the 4.6x write amplification seen in round 3).
__global__ __launch_bounds__(256) void attn_kernel(
    const float* __restrict__ qk, const float* __restrict__ inv_scale,
    const float* __restrict__ v, float* __restrict__ out) {
  __shared__ float qkrow[NN];      // 4 KB
  __shared__ float red[8];
  __shared__ int   surv[NN];       // 4 KB (worst case dense -> still correct)
  __shared__ float Pl[16][130];    // P chunk [s][d]
  __shared__ float Vs[16][132];    // V chunk [s][k]
  __shared__ float sdv[DD];
  __shared__ float rsl[DD];
  __shared__ int   cnt;

  const int n = blockIdx.x;
  const int t = threadIdx.x;

  const float4 q4 = *(const float4*)&qk[(size_t)n * NN + t * 4];
  *(float4*)&qkrow[t * 4] = q4;
  float mx = fmaxf(fmaxf(q4.x, q4.y), fmaxf(q4.z, q4.w));
#pragma unroll
  for (int o = 32; o > 0; o >>= 1) mx = fmaxf(mx, __shfl_xor(mx, o));
  if ((t & 63) == 0) red[t >> 6] = mx;
  float iv = 0.f;
  if (t < DD) { iv = inv_scale[n * DD + t]; sdv[t] = 1.0f / iv; }
  float miv = iv;
#pragma unroll
  for (int o = 32; o > 0; o >>= 1) miv = fmaxf(miv, __shfl_xor(miv, o));
  if ((t & 63) == 0) red[4 + (t >> 6)] = miv;
  if (t == 0) cnt = 0;
  __syncthreads();
  const float qkmax = fmaxf(fmaxf(red[0], red[1]), fmaxf(red[2], red[3]));
  const float maxinv = fmaxf(red[4], red[5]);
  const float th = qkmax - 30.f * maxinv;

  {
    const float qv[4] = {q4.x, q4.y, q4.z, q4.w};
#pragma unroll
    for (int j = 0; j < 4; ++j)
      if (qv[j] > th) { const int p = atomicAdd(&cnt, 1); surv[p] = t * 4 + j; }
  }
  __syncthreads();
  const int K = cnt;

  const int k4 = (t & 31) * 4;
  const int dbase = t >> 5;       // 0..7
  float4 acc4[16];
#pragma unroll
  for (int g = 0; g < 16; ++g) acc4[g] = make_float4(0.f, 0.f, 0.f, 0.f);
  float Sloc = 0.f;               // valid for t < 128 (d = t)

  for (int c0 = 0; c0 < K; c0 += 16) {
    const int C = min(16, K - c0);
    __syncthreads();
    if (t < DD) {
      const float sd = sdv[t];
      const uint32_t dg = ((uint32_t)(n * DD + t)) << 10;
      for (int s = 0; s < C; ++s) {
        const int m = surv[c0 + s];
        const float arg = (qkrow[m] - qkmax) * sd;
        const float e = __expf(arg);
        Sloc += e;
        float p = 0.f;
        if (arg > -30.f) {
          if (keep_mask(dg + (uint32_t)m)) p = e;
        }
        Pl[s][t] = p;
      }
    } else {
      const int u = t - 128;
      for (int slot = u; slot < C * 32; slot += 128) {
        const int s = slot >> 5, c = (slot & 31) * 4;
        *(float4*)&Vs[s][c] = *(const float4*)&v[(size_t)surv[c0 + s] * DD + c];
      }
    }
    __syncthreads();
    for (int s = 0; s < C; ++s) {
      const float4 vv = *(const float4*)&Vs[s][k4];
#pragma unroll
      for (int g = 0; g < 16; ++g) {
        const float p = Pl[s][g * 8 + dbase];
        acc4[g].x = fmaf(p, vv.x, acc4[g].x);
        acc4[g].y = fmaf(p, vv.y, acc4[g].y);
        acc4[g].z = fmaf(p, vv.z, acc4[g].z);
        acc4[g].w = fmaf(p, vv.w, acc4[g].w);
      }
    }
  }

  __syncthreads();
  if (t < DD) rsl[t] = 1.0f / (Sloc * 0.6f);
  __syncthreads();
  float* op = &out[(size_t)n * (DD * DD) + t * 4];
#pragma unroll
  for (int g = 0; g < 16; ++g) {
    const float rs = rsl[g * 8 + dbase];
    float4 r = acc4[g];
    r.x *= rs; r.y *= rs; r.z *= rs; r.w *= rs;
    *(float4*)&op[g * 1024] = r;
  }
}

// ---- launch --------------------------------------------------------------
extern "C" void kernel_launch(void* const* d_in, const int* in_sizes, int n_in,
                              void* d_out, int out_size, void* d_ws, size_t ws_size,
                              hipStream_t stream) {
  const float* x1 = (const float*)d_in[0];
  const float* x2 = (const float*)d_in[1];
  const float* x3 = (const float*)d_in[2];
  const float* x4 = (const float*)d_in[3];
  const float* W  = (const float*)d_in[4];
  const float* b  = (const float*)d_in[5];
  float* out = (float*)d_out;

  float* ws  = (float*)d_ws;
  float* q   = ws;                  // 1024*128
  float* k   = ws + 131072;
  float* v   = ws + 262144;
  float* sc  = ws + 393216;
  float* inv = ws + 524288;
  float* qkm = ws + 655360;         // 1024*1024

  lin_kernel<<<dim3(64, 4), 256, 0, stream>>>(x1, x2, x3, x4, W, b, q, k, v, sc);
  mid_kernel<<<dim3(384), 256, 0, stream>>>(q, k, sc, qkm, inv);
  attn_kernel<<<NN, 256, 0, stream>>>(qkm, inv, v, out);
}

// Round 6
// 118.596 us; speedup vs baseline: 1.1986x; 1.1986x over previous
//
#include <hip/hip_runtime.h>
#include <stdint.h>
#include <math.h>

static constexpr int NN  = 1024;   // N
static constexpr int DIN = 512;    // D_IN
static constexpr int DD  = 128;    // D_OUT

// ---- threefry2x32, key = jax.random.key(42) => (0,42), partitionable ----
__device__ __forceinline__ uint32_t rotl32(uint32_t x, uint32_t r) {
  return (x << r) | (x >> (32u - r));
}

__device__ __forceinline__ bool keep_mask(uint32_t idx) {
  uint32_t x0 = 0u, x1 = idx;
  const uint32_t k0 = 0u, k1 = 42u;
  const uint32_t k2 = k0 ^ k1 ^ 0x1BD11BDAu;
  x0 += k0; x1 += k1;
#define TF_ROUND(r) { x0 += x1; x1 = rotl32(x1, r); x1 ^= x0; }
  TF_ROUND(13u) TF_ROUND(15u) TF_ROUND(26u) TF_ROUND(6u)
  x0 += k1; x1 += k2 + 1u;
  TF_ROUND(17u) TF_ROUND(29u) TF_ROUND(16u) TF_ROUND(24u)
  x0 += k2; x1 += k0 + 2u;
  TF_ROUND(13u) TF_ROUND(15u) TF_ROUND(26u) TF_ROUND(6u)
  x0 += k0; x1 += k1 + 3u;
  TF_ROUND(17u) TF_ROUND(29u) TF_ROUND(16u) TF_ROUND(24u)
  x0 += k1; x1 += k2 + 4u;
  TF_ROUND(13u) TF_ROUND(15u) TF_ROUND(26u) TF_ROUND(6u)
  x0 += k2; x1 += k0 + 5u;
#undef TF_ROUND
  const uint32_t bits = x0 ^ x1;
  const float u = __uint_as_float((bits >> 9) | 0x3f800000u) - 1.0f;
  return u < 0.6f;
}

// ---- K0: WTp[k4][d][kk] = W[d][k4*4+kk]  (grid 64, block 256) ------------
// One-time 256 KB transpose so lin can read W coalesced with d-per-lane.
__global__ __launch_bounds__(256) void wtrans_kernel(
    const float* __restrict__ W, float* __restrict__ WTp) {
  const int t = threadIdx.x;
  const int d = blockIdx.x * 2 + (t >> 7);
  const int k4 = t & 127;
  const float4 w = *(const float4*)&W[d * DIN + k4 * 4];
  *(float4*)&WTp[(size_t)k4 * (DD * 4) + d * 4] = w;
}

// ---- K1: q,k,v,scale = x_i @ W.T + b  (grid (128,4), block 256) ----------
// Latency-first design (R5 post-mortem: lin was latency-bound, not LDS-BW-
// bound). 512 blocks (2/CU), ONE barrier, no W staging: W read coalesced
// from WTp (L2-resident), X from LDS via wave-uniform broadcast b128 reads.
__global__ __launch_bounds__(256) void lin_kernel(
    const float* __restrict__ x1, const float* __restrict__ x2,
    const float* __restrict__ x3, const float* __restrict__ x4,
    const float* __restrict__ WTp, const float* __restrict__ bias,
    float* __restrict__ q, float* __restrict__ kk,
    float* __restrict__ v, float* __restrict__ sc) {
  __shared__ float Xs[8 * 516];    // 16.5 KB, stride 516 (bank-safe writes)
  const int t = threadIdx.x;
  const int n0 = blockIdx.x * 8;
  const int mat = blockIdx.y;
  const float* x = (mat == 0) ? x1 : (mat == 1) ? x2 : (mat == 2) ? x3 : x4;
  float* o = (mat == 0) ? q : (mat == 1) ? kk : (mat == 2) ? v : sc;

  // stage X: 8 rows x 512 (4 float4 per thread, coalesced)
#pragma unroll
  for (int it = 0; it < 4; ++it) {
    const int i = t + 256 * it;
    const int r = i >> 7, c = (i & 127) * 4;
    *(float4*)&Xs[r * 516 + c] = *(const float4*)&x[(size_t)(n0 + r) * DIN + c];
  }
  __syncthreads();

  const int d = t & 127;           // lane-contiguous d within each wave
  const int g2 = t >> 7;           // 0/1: which 4 n-rows (wave-uniform)
  float acc[4] = {0.f, 0.f, 0.f, 0.f};
  const float* wp = &WTp[d * 4];

#pragma unroll 4
  for (int k4 = 0; k4 < 128; ++k4) {
    const float4 w4 = *(const float4*)&wp[(size_t)k4 * (DD * 4)];
#pragma unroll
    for (int j = 0; j < 4; ++j) {
      const float4 xa = *(const float4*)&Xs[(g2 * 4 + j) * 516 + k4 * 4];
      acc[j] = fmaf(xa.x, w4.x, fmaf(xa.y, w4.y,
               fmaf(xa.z, w4.z, fmaf(xa.w, w4.w, acc[j]))));
    }
  }

  const float bd = bias[d];
#pragma unroll
  for (int j = 0; j < 4; ++j)
    o[(size_t)(n0 + g2 * 4 + j) * DD + d] = acc[j] + bd;
}

// ---- K2: fused qk = q@k.T (blocks 0..255) + colsoftmax (blocks 256..383) -
__global__ __launch_bounds__(256) void mid_kernel(
    const float* __restrict__ q, const float* __restrict__ kref,
    const float* __restrict__ sc, float* __restrict__ qkout,
    float* __restrict__ inv) {
  const int t = threadIdx.x;
  if (blockIdx.x < 256) {
    // ---- qk: 64x64 tile, 4x4 per thread ----
    __shared__ float qs[64 * 132];
    __shared__ float ks[64 * 132];
    const int tx = t & 15, ty = t >> 4;
    const int tm = (blockIdx.x & 15) * 64, tn = (blockIdx.x >> 4) * 64;
    for (int it = 0; it < 8; ++it) {
      const int i = t + 256 * it;
      const int r = i >> 5, c = (i & 31) * 4;
      *(float4*)&qs[r * 132 + c] = *(const float4*)&q[(tn + r) * DD + c];
      *(float4*)&ks[r * 132 + c] = *(const float4*)&kref[(tm + r) * DD + c];
    }
    __syncthreads();
    float acc[4][4] = {};
    for (int k0 = 0; k0 < DD; k0 += 4) {
      float4 qv[4], kv[4];
#pragma unroll
      for (int i = 0; i < 4; ++i) qv[i] = *(const float4*)&qs[(ty * 4 + i) * 132 + k0];
#pragma unroll
      for (int j = 0; j < 4; ++j) kv[j] = *(const float4*)&ks[(tx + 16 * j) * 132 + k0];
#pragma unroll
      for (int i = 0; i < 4; ++i)
#pragma unroll
        for (int j = 0; j < 4; ++j)
          acc[i][j] = fmaf(qv[i].x, kv[j].x,
                      fmaf(qv[i].y, kv[j].y,
                      fmaf(qv[i].z, kv[j].z,
                      fmaf(qv[i].w, kv[j].w, acc[i][j]))));
    }
#pragma unroll
    for (int i = 0; i < 4; ++i)
#pragma unroll
      for (int j = 0; j < 4; ++j)
        qkout[(size_t)(tn + ty * 4 + i) * NN + tm + tx + 16 * j] = acc[i][j];
  } else {
    // ---- column softmax over n for d = blockIdx.x - 256 ----
    __shared__ float red[256];
    const int d = blockIdx.x - 256;
    float vals[4];
    float mx = -INFINITY;
#pragma unroll
    for (int i = 0; i < 4; ++i) {
      vals[i] = sc[(size_t)(t + 256 * i) * DD + d];
      mx = fmaxf(mx, vals[i]);
    }
    red[t] = mx; __syncthreads();
    for (int s = 128; s > 0; s >>= 1) {
      if (t < s) red[t] = fmaxf(red[t], red[t + s]);
      __syncthreads();
    }
    mx = red[0]; __syncthreads();
    float e[4]; float sm = 0.f;
#pragma unroll
    for (int i = 0; i < 4; ++i) { e[i] = expf(vals[i] - mx); sm += e[i]; }
    red[t] = sm; __syncthreads();
    for (int s = 128; s > 0; s >>= 1) {
      if (t < s) red[t] += red[t + s];
      __syncthreads();
    }
    sm = red[0];
#pragma unroll
    for (int i = 0; i < 4; ++i)
      inv[(size_t)(t + 256 * i) * DD + d] = e[i] / sm;
  }
}

// ---- K3: sparse softmax-dropout-PV  (grid 1024, block 256) ---------------
// Survivor gate: qv > qkmax - 30*max_d(inv) => ~1-3 survivors of 1024.
// Thread t owns k4=(t&31)*4 and d in {g*8 + (t>>5)} -> store g covers
// out[n*16384 + g*1024 + t*4]: 1 KB contiguous per wave-store (no partial
// cachelines; fixed the 4.6x write amplification seen in round 3).
__global__ __launch_bounds__(256) void attn_kernel(
    const float* __restrict__ qk, const float* __restrict__ inv_scale,
    const float* __restrict__ v, float* __restrict__ out) {
  __shared__ float qkrow[NN];      // 4 KB
  __shared__ float red[8];
  __shared__ int   surv[NN];       // 4 KB (worst case dense -> still correct)
  __shared__ float Pl[16][130];    // P chunk [s][d]
  __shared__ float Vs[16][132];    // V chunk [s][k]
  __shared__ float sdv[DD];
  __shared__ float rsl[DD];
  __shared__ int   cnt;

  const int n = blockIdx.x;
  const int t = threadIdx.x;

  const float4 q4 = *(const float4*)&qk[(size_t)n * NN + t * 4];
  *(float4*)&qkrow[t * 4] = q4;
  float mx = fmaxf(fmaxf(q4.x, q4.y), fmaxf(q4.z, q4.w));
#pragma unroll
  for (int o = 32; o > 0; o >>= 1) mx = fmaxf(mx, __shfl_xor(mx, o));
  if ((t & 63) == 0) red[t >> 6] = mx;
  float iv = 0.f;
  if (t < DD) { iv = inv_scale[n * DD + t]; sdv[t] = 1.0f / iv; }
  float miv = iv;
#pragma unroll
  for (int o = 32; o > 0; o >>= 1) miv = fmaxf(miv, __shfl_xor(miv, o));
  if ((t & 63) == 0) red[4 + (t >> 6)] = miv;
  if (t == 0) cnt = 0;
  __syncthreads();
  const float qkmax = fmaxf(fmaxf(red[0], red[1]), fmaxf(red[2], red[3]));
  const float maxinv = fmaxf(red[4], red[5]);
  const float th = qkmax - 30.f * maxinv;

  {
    const float qv[4] = {q4.x, q4.y, q4.z, q4.w};
#pragma unroll
    for (int j = 0; j < 4; ++j)
      if (qv[j] > th) { const int p = atomicAdd(&cnt, 1); surv[p] = t * 4 + j; }
  }
  __syncthreads();
  const int K = cnt;

  const int k4 = (t & 31) * 4;
  const int dbase = t >> 5;       // 0..7
  float4 acc4[16];
#pragma unroll
  for (int g = 0; g < 16; ++g) acc4[g] = make_float4(0.f, 0.f, 0.f, 0.f);
  float Sloc = 0.f;               // valid for t < 128 (d = t)

  for (int c0 = 0; c0 < K; c0 += 16) {
    const int C = min(16, K - c0);
    __syncthreads();
    if (t < DD) {
      const float sd = sdv[t];
      const uint32_t dg = ((uint32_t)(n * DD + t)) << 10;
      for (int s = 0; s < C; ++s) {
        const int m = surv[c0 + s];
        const float arg = (qkrow[m] - qkmax) * sd;
        const float e = __expf(arg);
        Sloc += e;
        float p = 0.f;
        if (arg > -30.f) {
          if (keep_mask(dg + (uint32_t)m)) p = e;
        }
        Pl[s][t] = p;
      }
    } else {
      const int u = t - 128;
      for (int slot = u; slot < C * 32; slot += 128) {
        const int s = slot >> 5, c = (slot & 31) * 4;
        *(float4*)&Vs[s][c] = *(const float4*)&v[(size_t)surv[c0 + s] * DD + c];
      }
    }
    __syncthreads();
    for (int s = 0; s < C; ++s) {
      const float4 vv = *(const float4*)&Vs[s][k4];
#pragma unroll
      for (int g = 0; g < 16; ++g) {
        const float p = Pl[s][g * 8 + dbase];
        acc4[g].x = fmaf(p, vv.x, acc4[g].x);
        acc4[g].y = fmaf(p, vv.y, acc4[g].y);
        acc4[g].z = fmaf(p, vv.z, acc4[g].z);
        acc4[g].w = fmaf(p, vv.w, acc4[g].w);
      }
    }
  }

  __syncthreads();
  if (t < DD) rsl[t] = 1.0f / (Sloc * 0.6f);
  __syncthreads();
  float* op = &out[(size_t)n * (DD * DD) + t * 4];
#pragma unroll
  for (int g = 0; g < 16; ++g) {
    const float rs = rsl[g * 8 + dbase];
    float4 r = acc4[g];
    r.x *= rs; r.y *= rs; r.z *= rs; r.w *= rs;
    *(float4*)&op[g * 1024] = r;
  }
}

// ---- launch --------------------------------------------------------------
extern "C" void kernel_launch(void* const* d_in, const int* in_sizes, int n_in,
                              void* d_out, int out_size, void* d_ws, size_t ws_size,
                              hipStream_t stream) {
  const float* x1 = (const float*)d_in[0];
  const float* x2 = (const float*)d_in[1];
  const float* x3 = (const float*)d_in[2];
  const float* x4 = (const float*)d_in[3];
  const float* W  = (const float*)d_in[4];
  const float* b  = (const float*)d_in[5];
  float* out = (float*)d_out;

  float* ws   = (float*)d_ws;
  float* q    = ws;                 // 1024*128
  float* k    = ws + 131072;
  float* v    = ws + 262144;
  float* sc   = ws + 393216;
  float* inv  = ws + 524288;
  float* qkm  = ws + 655360;        // 1024*1024
  float* WTp  = ws + 1703936;       // 512*128 transposed W

  wtrans_kernel<<<dim3(64), 256, 0, stream>>>(W, WTp);
  lin_kernel<<<dim3(128, 4), 256, 0, stream>>>(x1, x2, x3, x4, WTp, b, q, k, v, sc);
  mid_kernel<<<dim3(384), 256, 0, stream>>>(q, k, sc, qkm, inv);
  attn_kernel<<<NN, 256, 0, stream>>>(qkm, inv, v, out);
}